// Round 5
// baseline (56.022 us; speedup 1.0000x reference)
//
#include <hip/hip_runtime.h>

#define SS 4096
#define DD 1024
#define EE 128
#define SCALE 0.08838834764831845f   // 1/sqrt(128)

typedef __bf16 bf16x8 __attribute__((ext_vector_type(8)));
typedef __bf16 bf16x4 __attribute__((ext_vector_type(4)));
typedef float  f32x4  __attribute__((ext_vector_type(4)));

__device__ __forceinline__ void gload16(const void* g, void* l) {
  __builtin_amdgcn_global_load_lds(
      (const __attribute__((address_space(1))) void*)g,
      (__attribute__((address_space(3))) void*)l, 16, 0, 0);
}

// ---------------------------------------------------------------------------
// K0: cast x (8192x1024) and W (q|k|v, 384x1024) to bf16.
// grid 2144 x 256 thr; blocks 0-2047 -> x, 2048-2143 -> W (32 blocks each).
// ---------------------------------------------------------------------------
__global__ __launch_bounds__(256) void cast_kernel(
    const float* __restrict__ x,  const float* __restrict__ qW,
    const float* __restrict__ kW, const float* __restrict__ vW,
    __bf16* __restrict__ xb, __bf16* __restrict__ Wb)
{
  const int blk = blockIdx.x, tid = threadIdx.x;
  const float* src;
  __bf16* dst;
  size_t base;
  if (blk < 2048) { src = x; dst = xb; base = (size_t)blk * 4096; }
  else {
    int wb2 = blk - 2048;                // 0..95
    int m = wb2 >> 5;                    // 0..2
    src = (m == 0) ? qW : (m == 1 ? kW : vW);
    dst = Wb + (size_t)m * EE * DD;
    base = (size_t)(wb2 & 31) * 4096;
  }
  #pragma unroll
  for (int j = 0; j < 2; ++j) {
    size_t o = base + (size_t)j * 2048 + (size_t)tid * 8;
    float4 u0 = *(const float4*)&src[o];
    float4 u1 = *(const float4*)&src[o + 4];
    bf16x8 v = { (__bf16)u0.x, (__bf16)u0.y, (__bf16)u0.z, (__bf16)u0.w,
                 (__bf16)u1.x, (__bf16)u1.y, (__bf16)u1.z, (__bf16)u1.w };
    *(bf16x8*)&dst[o] = v;
  }
}

// ---------------------------------------------------------------------------
// K1: fused QKV projection, m97-style: BM=128 BN=64 BK=64, global_load_lds
// staging, double-buffered linear LDS, one barrier per K-step.
// grid (64 rtiles, 6 ctiles) x 512 thr (8 waves = 4 row x 2 col; wave 32x32).
// ctile 0,1 -> Q (row-major +bias); 2,3 -> KT; 4,5 -> VT (LDS transpose).
// ---------------------------------------------------------------------------
__global__ __launch_bounds__(512) void proj_kernel(
    const __bf16* __restrict__ xb, const __bf16* __restrict__ Wb,
    const float* __restrict__ qB, const float* __restrict__ kB,
    const float* __restrict__ vB,
    __bf16* __restrict__ Qbf, __bf16* __restrict__ KT, __bf16* __restrict__ VT)
{
  __shared__ __attribute__((aligned(16))) __bf16 ldsA[2][128 * 64];
  __shared__ __attribute__((aligned(16))) __bf16 ldsB[2][64 * 64];

  const int tid  = threadIdx.x;
  const int w    = tid >> 6, lane = tid & 63;
  const int l15  = lane & 15, l4 = lane >> 4;
  const int wr   = w >> 1, wc = w & 1;        // wave tile 32r x 32c
  const int row0 = blockIdx.x * 128;          // flat row [0,8192)
  const int ct   = blockIdx.y;                // 0..5
  const int g0   = ct * 64;                   // global col base [0,384)

  // staging addresses (per lane): A segs 2w,2w+1; B seg w
  const int sr = lane >> 3, sc = (lane & 7) * 8;   // row-in-seg, col
  const __bf16* gA0 = xb + (size_t)(row0 + (2*w)*8   + sr) * DD + sc;
  const __bf16* gA1 = xb + (size_t)(row0 + (2*w+1)*8 + sr) * DD + sc;
  const __bf16* gB  = Wb + (size_t)(g0   + w*8       + sr) * DD + sc;

  f32x4 acc[2][2] = {};

#define STAGE(P, T) {                                                        \
    const int k0_ = (T) * 64;                                                \
    gload16(gA0 + k0_, &ldsA[P][(2*w)*512]);                                 \
    gload16(gA1 + k0_, &ldsA[P][(2*w+1)*512]);                               \
    gload16(gB  + k0_, &ldsB[P][w*512]);                                     }

#define COMPUTE(P) {                                                         \
    _Pragma("unroll") for (int ks = 0; ks < 2; ++ks) {                       \
      const int ko = ks * 32 + l4 * 8;                                       \
      bf16x8 a0 = *(const bf16x8*)&ldsA[P][(wr*32      + l15)*64 + ko];      \
      bf16x8 a1 = *(const bf16x8*)&ldsA[P][(wr*32 + 16 + l15)*64 + ko];      \
      bf16x8 b0 = *(const bf16x8*)&ldsB[P][(wc*32      + l15)*64 + ko];      \
      bf16x8 b1 = *(const bf16x8*)&ldsB[P][(wc*32 + 16 + l15)*64 + ko];      \
      acc[0][0] = __builtin_amdgcn_mfma_f32_16x16x32_bf16(a0,b0,acc[0][0],0,0,0); \
      acc[0][1] = __builtin_amdgcn_mfma_f32_16x16x32_bf16(a0,b1,acc[0][1],0,0,0); \
      acc[1][0] = __builtin_amdgcn_mfma_f32_16x16x32_bf16(a1,b0,acc[1][0],0,0,0); \
      acc[1][1] = __builtin_amdgcn_mfma_f32_16x16x32_bf16(a1,b1,acc[1][1],0,0,0); \
    } }

  STAGE(0, 0);
  __syncthreads();
  for (int t = 0; t < 15; ++t) {
    STAGE((t + 1) & 1, t + 1);
    COMPUTE(t & 1);
    __syncthreads();
  }
  COMPUTE(1);
  __syncthreads();
#undef STAGE
#undef COMPUTE

  const float* bias = (g0 < 128) ? qB : (g0 < 256 ? kB : vB);
  const int bofs = (g0 < 128) ? g0 : (g0 < 256 ? g0 - 128 : g0 - 256);

  if (ct < 2) {                                  // Q: row-major store
    #pragma unroll
    for (int m = 0; m < 2; ++m)
      #pragma unroll
      for (int n = 0; n < 2; ++n) {
        const int col = wc * 32 + n * 16 + l15;
        const float bv = bias[bofs + col];
        #pragma unroll
        for (int r = 0; r < 4; ++r) {
          const int row = row0 + wr * 32 + m * 16 + l4 * 4 + r;
          Qbf[(size_t)row * EE + g0 + col] = (__bf16)(acc[m][n][r] + bv);
        }
      }
  } else {                                       // K/V: transpose via LDS
    __bf16* Tb = (__bf16*)ldsA;                  // [64 cols][128 rows chunkXOR]
    #pragma unroll
    for (int m = 0; m < 2; ++m)
      #pragma unroll
      for (int n = 0; n < 2; ++n) {
        const int tc = wc * 32 + n * 16 + l15;
        const float bv = bias[bofs + tc];
        #pragma unroll
        for (int r = 0; r < 4; ++r) {
          const int rl = wr * 32 + m * 16 + l4 * 4 + r;
          Tb[tc * 128 + (((rl >> 3) ^ (tc & 7)) << 3) + (rl & 7)] =
              (__bf16)(acc[m][n][r] + bv);
        }
      }
    __syncthreads();
    if (tid < 256) {
      const int col = tid >> 2, p2 = tid & 3;
      const int b = row0 >> 12, s0 = row0 & 4095;
      __bf16* dst = (ct < 4)
          ? &KT[((size_t)b * EE + (ct - 2) * 64 + col) * SS + s0]
          : &VT[((size_t)b * EE + (ct - 4) * 64 + col) * SS + s0];
      #pragma unroll
      for (int j = 0; j < 4; ++j) {
        const int ch = p2 * 4 + j;
        bf16x8 v = *(const bf16x8*)&Tb[col * 128 + ((ch ^ (col & 7)) << 3)];
        *(bf16x8*)&dst[ch * 8] = v;
      }
    }
  }
}

// ---------------------------------------------------------------------------
// K2: partial K^T V.  grid (32 chunks, 2 batches) x 256 threads (4 waves).
// ---------------------------------------------------------------------------
__global__ __launch_bounds__(256) void ktv_kernel(
    const __bf16* __restrict__ KT, const __bf16* __restrict__ VT,
    float* __restrict__ part)
{
  const int c = blockIdx.x, b = blockIdx.y;
  const int tid = threadIdx.x;
  const int w = tid >> 6, lane = tid & 63;
  const int l15 = lane & 15, l4 = lane >> 4;
  const int s0 = c * 128;
  const __bf16* Kb = KT + (size_t)b * EE * SS;
  const __bf16* Vb = VT + (size_t)b * EE * SS;

  f32x4 acc[8][2] = {};
  #pragma unroll
  for (int ks = 0; ks < 4; ++ks) {
    const int s = s0 + ks * 32 + 8 * l4;
    bf16x8 bv[2];
    #pragma unroll
    for (int j = 0; j < 2; ++j)
      bv[j] = *(const bf16x8*)&Vb[(size_t)(w * 32 + j * 16 + l15) * SS + s];
    #pragma unroll
    for (int i = 0; i < 8; ++i) {
      bf16x8 av = *(const bf16x8*)&Kb[(size_t)(i * 16 + l15) * SS + s];
      acc[i][0] = __builtin_amdgcn_mfma_f32_16x16x32_bf16(av, bv[0], acc[i][0], 0, 0, 0);
      acc[i][1] = __builtin_amdgcn_mfma_f32_16x16x32_bf16(av, bv[1], acc[i][1], 0, 0, 0);
    }
  }
  float* P = part + (size_t)(b * 32 + c) * 16384;
  #pragma unroll
  for (int i = 0; i < 8; ++i)
    #pragma unroll
    for (int j = 0; j < 2; ++j)
      #pragma unroll
      for (int r = 0; r < 4; ++r) {
        int e = i * 16 + l4 * 4 + r;
        int f = w * 32 + j * 16 + l15;
        P[e * 128 + f] = acc[i][j][r];
      }
}

// ---------------------------------------------------------------------------
// K3: reduce 32 partials -> MT[b][f][e] = scale * sum (bf16, transposed)
// ---------------------------------------------------------------------------
__global__ __launch_bounds__(256) void reduce_kernel(
    const float* __restrict__ part, __bf16* __restrict__ MT)
{
  const int b = blockIdx.y;
  const int e = blockIdx.x * 8 + (threadIdx.x >> 5);
  const int f4 = (threadIdx.x & 31) * 4;
  f32x4 s = {};
  for (int cc = 0; cc < 32; ++cc)
    s += *(const f32x4*)&part[(size_t)(b * 32 + cc) * 16384 + e * 128 + f4];
  #pragma unroll
  for (int i = 0; i < 4; ++i)
    MT[((size_t)b * EE + f4 + i) * EE + e] = (__bf16)(SCALE * s[i]);
}

// ---------------------------------------------------------------------------
// K4: O = Q * M  (MT[f][e]).  grid (64, 2) x 256 threads.
// ---------------------------------------------------------------------------
__global__ __launch_bounds__(256) void qm_kernel(
    const __bf16* __restrict__ Qbf, const __bf16* __restrict__ MT,
    float* __restrict__ out)
{
  const int b = blockIdx.y;
  const int tid = threadIdx.x;
  const int w = tid >> 6, lane = tid & 63;
  const int l15 = lane & 15, l4 = lane >> 4;
  const int row0 = blockIdx.x * 64 + w * 16;
  const __bf16* Qb = Qbf + (size_t)b * SS * EE;
  const __bf16* Mb = MT + (size_t)b * EE * EE;

  f32x4 acc[8] = {};
  #pragma unroll
  for (int ks = 0; ks < 4; ++ks) {
    const int e = ks * 32 + 8 * l4;
    bf16x8 av = *(const bf16x8*)&Qb[(size_t)(row0 + l15) * EE + e];
    #pragma unroll
    for (int j = 0; j < 8; ++j) {
      bf16x8 bv = *(const bf16x8*)&Mb[(size_t)(j * 16 + l15) * EE + e];
      acc[j] = __builtin_amdgcn_mfma_f32_16x16x32_bf16(av, bv, acc[j], 0, 0, 0);
    }
  }
  #pragma unroll
  for (int j = 0; j < 8; ++j)
    #pragma unroll
    for (int r = 0; r < 4; ++r) {
      int srow = row0 + l4 * 4 + r;
      int f = j * 16 + l15;
      out[((size_t)b * SS + srow) * EE + f] = acc[j][r];
    }
}

extern "C" void kernel_launch(void* const* d_in, const int* in_sizes, int n_in,
                              void* d_out, int out_size, void* d_ws, size_t ws_size,
                              hipStream_t stream) {
  const float* x  = (const float*)d_in[0];
  const float* qW = (const float*)d_in[1];
  const float* qB = (const float*)d_in[2];
  const float* kW = (const float*)d_in[3];
  const float* kB = (const float*)d_in[4];
  const float* vW = (const float*)d_in[5];
  const float* vB = (const float*)d_in[6];
  float* out = (float*)d_out;

  char* base = (char*)d_ws;
  __bf16* xb  = (__bf16*)(base);                         // 16 MB
  __bf16* Wb  = (__bf16*)(base + (16u << 20));           // 768 KB
  __bf16* Qbf = (__bf16*)(base + (17u << 20));           // 2 MB
  __bf16* KT  = (__bf16*)(base + (19u << 20));           // 2 MB
  __bf16* VT  = (__bf16*)(base + (21u << 20));           // 2 MB
  float*  part= (float*) (base + (23u << 20));           // 4 MB
  __bf16* MT  = (__bf16*)(base + (27u << 20));           // 64 KB

  cast_kernel  <<<dim3(2144),  256, 0, stream>>>(x, qW, kW, vW, xb, Wb);
  proj_kernel  <<<dim3(64, 6), 512, 0, stream>>>(xb, Wb, qB, kB, vB, Qbf, KT, VT);
  ktv_kernel   <<<dim3(32, 2), 256, 0, stream>>>(KT, VT, part);
  reduce_kernel<<<dim3(16, 2), 256, 0, stream>>>(part, MT);
  qm_kernel    <<<dim3(64, 2), 256, 0, stream>>>(Qbf, MT, out);
}